// Round 1
// baseline (30.413 us; speedup 1.0000x reference)
//
#include <hip/hip_runtime.h>
#include <hip/hip_bf16.h>
#include <float.h>

// Kernel 1: argmax over vocab for each (t, b) row.
// x layout: (seq_len, batch, vocab) row-major, rows of `vocab` contiguous floats.
// One 64-lane wave per row. Output ml stored TRANSPOSED: ml[b * seq_len + t].
__global__ void ctc_argmax_kernel(const float* __restrict__ x,
                                  int* __restrict__ ml,
                                  int seq_len, int batch, int vocab) {
    const int waves_per_block = blockDim.x >> 6;
    const int row = blockIdx.x * waves_per_block + (threadIdx.x >> 6);
    const int nrows = seq_len * batch;
    if (row >= nrows) return;
    const int lane = threadIdx.x & 63;

    const float* p = x + (size_t)row * vocab;

    float best = -FLT_MAX;
    int bidx = vocab;  // sentinel larger than any real index

    // Main loop: float4 per lane, wave reads contiguous 1KiB per iteration.
    const int vocab4 = vocab & ~3;
    for (int base = lane * 4; base + 4 <= vocab4 + 1 ? base + 3 < vocab4 : false; base += 256) {
        // (guard written oddly to avoid compiler complaints; simple: base+3 < vocab4)
        float4 v = *reinterpret_cast<const float4*>(p + base);
        if (v.x > best) { best = v.x; bidx = base + 0; }
        if (v.y > best) { best = v.y; bidx = base + 1; }
        if (v.z > best) { best = v.z; bidx = base + 2; }
        if (v.w > best) { best = v.w; bidx = base + 3; }
    }
    // Scalar tail (only if vocab % 4 != 0). Tail indices are larger than all
    // main-loop indices, strict '>' keeps the earlier occurrence.
    for (int i = vocab4 + lane; i < vocab; i += 64) {
        float v = p[i];
        if (v > best) { best = v; bidx = i; }
    }

    // Wave butterfly reduce: larger value wins; on tie, lower index wins.
    #pragma unroll
    for (int off = 32; off >= 1; off >>= 1) {
        float oval = __shfl_down(best, off, 64);
        int oidx = __shfl_down(bidx, off, 64);
        if (oval > best || (oval == best && oidx < bidx)) { best = oval; bidx = oidx; }
    }

    if (lane == 0) {
        const int t = row / batch;
        const int b = row - t * batch;
        ml[(size_t)b * seq_len + t] = bidx;
    }
}

// Kernel 2: per-batch removal of blanks and consecutive duplicates + left-pack.
// One block (256 threads) per batch element.
__global__ void ctc_compact_kernel(const int* __restrict__ ml,
                                   const int* __restrict__ lengths,
                                   const int* __restrict__ blank_ptr,
                                   int* __restrict__ tokens,
                                   int* __restrict__ out_lengths,
                                   int seq_len, int batch) {
    constexpr int MAXPER = 16;
    const int b = blockIdx.x;
    if (b >= batch) return;
    const int blank = *blank_ptr;
    const int len = lengths[b];
    const int* row = ml + (size_t)b * seq_len;
    int* out = tokens + (size_t)b * seq_len;

    const int tid = threadIdx.x;
    const int nthr = blockDim.x;
    const int per = (seq_len + nthr - 1) / nthr;  // 8 for 2048/256

    // Fill the whole output row with -1 first.
    for (int i = tid; i < seq_len; i += nthr) out[i] = -1;

    // Each thread owns `per` consecutive timesteps [t0, t0+per).
    const int t0 = tid * per;
    int vals[MAXPER];
    unsigned keep_mask = 0;
    int cnt = 0;
    int prev = (t0 == 0) ? -1 : ((t0 - 1 < seq_len) ? row[t0 - 1] : -1);
    for (int j = 0; j < per; ++j) {
        const int t = t0 + j;
        if (t >= seq_len) break;
        const int v = row[t];
        const bool valid = t < len;
        const bool k = valid && (v != blank) && (prev == blank || v != prev);
        vals[j] = v;
        if (k) { keep_mask |= (1u << j); ++cnt; }
        prev = v;
    }

    // Block-wide exclusive prefix sum of cnt (in thread order).
    __shared__ int warp_sums[8];
    const int lane = tid & 63;
    const int wid = tid >> 6;
    int incl = cnt;
    #pragma unroll
    for (int off = 1; off < 64; off <<= 1) {
        int n = __shfl_up(incl, off, 64);
        if (lane >= off) incl += n;
    }
    if (lane == 63) warp_sums[wid] = incl;
    __syncthreads();   // also orders -1 fill before the scatter below

    int wbase = 0;
    for (int w = 0; w < wid; ++w) wbase += warp_sums[w];
    int pos = wbase + incl - cnt;  // exclusive prefix for this thread

    for (int j = 0; j < per; ++j) {
        if (keep_mask & (1u << j)) out[pos++] = vals[j];
    }

    if (tid == 0) {
        int total = 0;
        const int nwaves = nthr >> 6;
        for (int w = 0; w < nwaves; ++w) total += warp_sums[w];
        out_lengths[b] = total;
    }
}

extern "C" void kernel_launch(void* const* d_in, const int* in_sizes, int n_in,
                              void* d_out, int out_size, void* d_ws, size_t ws_size,
                              hipStream_t stream) {
    const float* x = (const float*)d_in[0];
    const int* lengths = (const int*)d_in[1];
    const int* blank_ptr = (const int*)d_in[2];

    const int batch = in_sizes[1];
    const int seq_len = (out_size - batch) / batch;      // tokens is (batch, seq_len)
    const int vocab = in_sizes[0] / (seq_len * batch);

    int* tokens = (int*)d_out;                  // (batch, seq_len)
    int* out_lengths = (int*)d_out + (size_t)batch * seq_len;  // (batch,)
    int* ml = (int*)d_ws;                       // (batch, seq_len) argmax symbols

    // Kernel 1: one wave per (t,b) row; 4 waves per 256-thread block.
    const int nrows = seq_len * batch;
    const int waves_per_block = 4;
    const int blocks1 = (nrows + waves_per_block - 1) / waves_per_block;
    ctc_argmax_kernel<<<blocks1, waves_per_block * 64, 0, stream>>>(
        x, ml, seq_len, batch, vocab);

    // Kernel 2: one block per batch element.
    ctc_compact_kernel<<<batch, 256, 0, stream>>>(
        ml, lengths, blank_ptr, tokens, out_lengths, seq_len, batch);
}